// Round 11
// baseline (7586.417 us; speedup 1.0000x reference)
//
#include <hip/hip_runtime.h>
#include <hip/hip_bf16.h>

#define T_ 32
#define B_ 16
#define I_ 512
#define H_ 512
#define OFF_ 441
#define NR_ 71           // I_ - OFF_
#define NC_ 2556         // NR_*(NR_+1)/2
#define G4_ (4*NC_)      // 10224
#define NCP_ 2560        // K padded
#define NPR_ 10240       // padded gate-permuted row count
#define NTIL_ 640        // NPR_/16
#define PBLK_ 640        // persistent blocks (2 n-tiles each)

typedef __attribute__((ext_vector_type(8))) short bf16x8;
typedef __attribute__((ext_vector_type(4))) float f32x4;

__device__ __forceinline__ ushort bfc(float f) {
    __hip_bfloat16 h = __float2bfloat16(f);
    return *(ushort*)&h;
}
__device__ __forceinline__ float b2f(ushort u) {
    return __uint_as_float((uint)u << 16);
}
__device__ __forceinline__ float sigf(float x) { return 1.f / (1.f + expf(-x)); }

// int8x8 (two uints) -> integer-valued bf16x8 (exact for |v|<=127)
__device__ __forceinline__ bf16x8 dq8(uint lo, uint hi) {
    union { bf16x8 v; ushort us[8]; } r;
    #pragma unroll
    for (int i = 0; i < 4; ++i) {
        int b0 = (int)(signed char)(lo >> (8 * i));
        int b1 = (int)(signed char)(hi >> (8 * i));
        r.us[i]     = (ushort)(__float_as_uint((float)b0) >> 16);
        r.us[i + 4] = (ushort)(__float_as_uint((float)b1) >> 16);
    }
    return r.v;
}

__global__ void k_zero(float* __restrict__ p, int n) {
    int i = blockIdx.x * 256 + threadIdx.x;
    if (i < n) p[i] = 0.f;
}

// x fp32 [512][512] -> bf16 same layout
__global__ void k_cvt_x(const float* __restrict__ x, ushort* __restrict__ xb) {
    int i = blockIdx.x * 256 + threadIdx.x;
    float4 v = ((const float4*)x)[i];
    ushort4 o; o.x = bfc(v.x); o.y = bfc(v.y); o.z = bfc(v.z); o.w = bfc(v.w);
    ((ushort4*)xb)[i] = o;
}

// Wih[l] fp32 [G4][512] -> bf16 gate-permuted [NPR][512]; row n' = 4*jc+q <- q*NC+jc
__global__ void k_cvt_w512p(const float* __restrict__ W0, const float* __restrict__ W1,
                            ushort* __restrict__ dst) {
    int l = blockIdx.z;
    const float* src = l ? W1 : W0;
    size_t idx = (size_t)blockIdx.x * 256 + threadIdx.x;
    int np = (int)(idx >> 7), kq = (int)(idx & 127);
    ushort4 o; o.x = 0; o.y = 0; o.z = 0; o.w = 0;
    int jc = np >> 2, q = np & 3;
    if (jc < NC_) {
        float4 v = *(const float4*)(src + ((size_t)q * NC_ + jc) * I_ + kq * 4);
        o.x = bfc(v.x); o.y = bfc(v.y); o.z = bfc(v.z); o.w = bfc(v.w);
    }
    ((ushort4*)(dst + ((size_t)l * NPR_ + np) * I_))[kq] = o;
}

// Whh[l] fp32 [G4][2556] -> int8 gate-permuted K-padded [NPR][2560] + per-row scale.
__global__ __launch_bounds__(256) void k_cvt_whh_i8(const float* __restrict__ W0,
        const float* __restrict__ W1,
        signed char* __restrict__ dst, float* __restrict__ sW) {
    const int l = blockIdx.z;
    const float* src = l ? W1 : W0;
    const int np = blockIdx.x * 4 + (threadIdx.x >> 6);
    const int lane = threadIdx.x & 63;
    const int jc = np >> 2, q = np & 3;
    float w[40];
    float mx = 0.f;
    if (jc < NC_) {
        const float* row = src + ((size_t)q * NC_ + jc) * NC_;
        #pragma unroll
        for (int i = 0; i < 40; ++i) {
            int k = lane + i * 64;
            w[i] = (k < NC_) ? row[k] : 0.f;
            mx = fmaxf(mx, fabsf(w[i]));
        }
    } else {
        #pragma unroll
        for (int i = 0; i < 40; ++i) w[i] = 0.f;
    }
    #pragma unroll
    for (int d = 1; d < 64; d <<= 1) mx = fmaxf(mx, __shfl_xor(mx, d));
    const float inv = (mx > 0.f) ? 127.f / mx : 0.f;
    signed char* orow = dst + ((size_t)l * NPR_ + np) * NCP_;
    #pragma unroll
    for (int i = 0; i < 40; ++i) {
        int k = lane + i * 64;
        orow[k] = (signed char)(int)rintf(w[i] * inv);
    }
    if (lane == 0) sW[(size_t)l * NPR_ + np] = (mx > 0.f) ? mx / 127.f : 0.f;
}

// MFMA input GEMM -> preT[l][n'][m] bf16, m = t*16+b; permuted bias added
__global__ __launch_bounds__(256) void k_gih_mfma(const ushort* __restrict__ Xbf,
        const ushort* __restrict__ Wp,
        const float* __restrict__ b0, const float* __restrict__ b1,
        ushort* __restrict__ preT) {
    const int l = blockIdx.z;
    const float* bb = l ? b1 : b0;
    const int wid = threadIdx.x >> 6, lane = threadIdx.x & 63;
    const int nt = blockIdx.x * 4 + wid;
    __shared__ ushort lds_a[32 * 64 * 8];
    const int srow = lane & 15, skq = (lane >> 4) * 8;
    const ushort* wp = Wp + ((size_t)l * NPR_ + nt * 16 + srow) * I_ + skq;
    f32x4 acc[32];
    #pragma unroll
    for (int mt = 0; mt < 32; ++mt) acc[mt] = (f32x4){0.f, 0.f, 0.f, 0.f};
    for (int ks = 0; ks < 16; ++ks) {
        #pragma unroll
        for (int i = 0; i < 8; ++i) {
            int mt = wid * 8 + i;
            bf16x8 xv = *(const bf16x8*)(Xbf + (size_t)(mt * 16 + srow) * I_ + ks * 32 + skq);
            *(bf16x8*)(lds_a + (mt * 64 + lane) * 8) = xv;
        }
        bf16x8 b = *(const bf16x8*)(wp + ks * 32);
        __syncthreads();
        #pragma unroll
        for (int mt = 0; mt < 32; ++mt) {
            bf16x8 a = *(const bf16x8*)(lds_a + (mt * 64 + lane) * 8);
            acc[mt] = __builtin_amdgcn_mfma_f32_16x16x32_bf16(a, b, acc[mt], 0, 0, 0);
        }
        __syncthreads();
    }
    const int n = nt * 16 + srow;
    const float bv = (n < G4_) ? bb[(size_t)(n & 3) * NC_ + (n >> 2)] : 0.f;
    const int r0 = (lane >> 4) * 4;
    ushort* po = preT + ((size_t)l * NPR_ + n) * 512;
    #pragma unroll
    for (int mt = 0; mt < 32; ++mt) {
        ushort4 o;
        o.x = bfc(acc[mt][0] + bv); o.y = bfc(acc[mt][1] + bv);
        o.z = bfc(acc[mt][2] + bv); o.w = bfc(acc[mt][3] + bv);
        *(ushort4*)(po + mt * 16 + r0) = o;
    }
}

// Persistent recurrent loop (weights STREAMED, not reg-resident).
// 640 blocks x 4 waves; block owns 2 adjacent n-tiles of ONE layer (blk<320 -> l=0).
// Shared h load feeds both items' MFMAs; c-state in registers; inline grid barrier.
__global__ __launch_bounds__(256, 3) void k_loop_p(const signed char* __restrict__ Wp8,
        const float* __restrict__ sW, const ushort* __restrict__ preT,
        ushort* __restrict__ hbf, float* __restrict__ hbuf,
        const float* __restrict__ scal_ih, const float* __restrict__ scal_hh,
        uint* __restrict__ bar) {
    __shared__ float gl[2][4][16][17];   // [item][wave][nlocal][b]
    const int blk = blockIdx.x;
    const int l = (blk >= PBLK_ / 2) ? 1 : 0;
    const int nt0 = blk * 2 - l * NTIL_;
    const int tid = threadIdx.x;
    const int w = tid >> 6, lane = tid & 63;
    const int col = lane & 15;
    const int kq = (lane >> 4) * 8;
    const int kbase = w * 640;
    const size_t HSpp = (size_t)2 * B_ * NCP_;
    const signed char* wp0 = Wp8 + ((size_t)l * NPR_ + nt0 * 16 + col) * NCP_ + kbase + kq;
    const signed char* wp1 = wp0 + (size_t)16 * NCP_;

    // gate-pass constants (threads 0..127: item = tid>>6, unit jq, batch b)
    float creg = 0.f;
    float swv[4]; int jc_g = NC_; int b_g = 0; int row0_g = 0; float sc_g = 0.f;
    if (tid < 128) {
        const int item = tid >> 6;
        const int tt = tid & 63;
        b_g = tt & 15;
        const int jq = tt >> 4;
        const int nt = nt0 + item;
        jc_g = nt * 4 + jq;
        row0_g = nt * 16 + jq * 4;
        #pragma unroll
        for (int q = 0; q < 4; ++q)
            swv[q] = sW[(size_t)l * NPR_ + row0_g + q];
        if (jc_g < NC_) sc_g = (l ? scal_hh : scal_ih)[jc_g];
    }

    for (int t = 0; t < T_; ++t) {
        // prefetch this step's preT operands (hidden under MFMA phase)
        float pv[4];
        if (tid < 128 && jc_g < NC_) {
            #pragma unroll
            for (int q = 0; q < 4; ++q)
                pv[q] = b2f(preT[((size_t)l * NPR_ + row0_g + q) * 512 + t * 16 + b_g]);
        }
        const ushort* hp = hbf + (size_t)(t & 1) * HSpp
                         + ((size_t)l * B_ + col) * NCP_ + kbase + kq;
        f32x4 acc0 = {0.f, 0.f, 0.f, 0.f};
        f32x4 acc1 = {0.f, 0.f, 0.f, 0.f};
        #pragma unroll 4
        for (int ks = 0; ks < 20; ++ks) {
            bf16x8 a = *(const bf16x8*)(hp + ks * 32);
            uint2 wb0 = *(const uint2*)(wp0 + ks * 32);
            uint2 wb1 = *(const uint2*)(wp1 + ks * 32);
            acc0 = __builtin_amdgcn_mfma_f32_16x16x32_bf16(a, dq8(wb0.x, wb0.y), acc0, 0, 0, 0);
            acc1 = __builtin_amdgcn_mfma_f32_16x16x32_bf16(a, dq8(wb1.x, wb1.y), acc1, 0, 0, 0);
        }
        const int m0 = (lane >> 4) * 4;
        #pragma unroll
        for (int v = 0; v < 4; ++v) {
            gl[0][w][col][m0 + v] = acc0[v];
            gl[1][w][col][m0 + v] = acc1[v];
        }
        __syncthreads();
        // gate pass: threads 0..127
        if (tid < 128 && jc_g < NC_) {
            const int item = tid >> 6;
            const int jq = (tid & 63) >> 4;
            float g[4];
            #pragma unroll
            for (int q = 0; q < 4; ++q) {
                float s = gl[item][0][jq * 4 + q][b_g] + gl[item][1][jq * 4 + q][b_g]
                        + gl[item][2][jq * 4 + q][b_g] + gl[item][3][jq * 4 + q][b_g];
                g[q] = s * swv[q] + pv[q];
            }
            float cn = sigf(g[1]) * creg + sigf(g[0]) * tanhf(g[2]);
            float hn = sigf(g[3]) * tanhf(cn);
            creg = cn;
            ushort* hout = hbf + (size_t)((t & 1) ^ 1) * HSpp + (size_t)l * B_ * NCP_;
            hout[(size_t)b_g * NCP_ + jc_g] = bfc(hn);
            hbuf[(((size_t)l * T_ + t) * B_ + b_g) * NC_ + jc_g] = hn * sc_g;
        }
        // ---- inline grid barrier (bar zeroed per launch; monotone within launch) ----
        __threadfence();
        __syncthreads();
        if (tid == 0) {
            __hip_atomic_fetch_add(bar, 1u, __ATOMIC_RELEASE, __HIP_MEMORY_SCOPE_AGENT);
            const uint tgt = (uint)PBLK_ * (uint)(t + 1);
            while (__hip_atomic_load(bar, __ATOMIC_ACQUIRE, __HIP_MEMORY_SCOPE_AGENT) < tgt)
                __builtin_amdgcn_s_sleep(2);
        }
        __syncthreads();
        __threadfence();
    }
}

// Bt[k][h] = idct_hid[h][k] for k < 71
__global__ void k_bt(const float* __restrict__ Bh, float* __restrict__ Bt) {
    int idx = blockIdx.x * 256 + threadIdx.x;
    if (idx < NR_ * H_) {
        int k = idx / H_, h = idx - k * H_;
        Bt[idx] = Bh[(size_t)h * H_ + k];
    }
}

// yih[t,b,h] = sum_k Bt[k,h] * v[k]; coeffs pre-scaled in hbuf
__global__ __launch_bounds__(256) void k_yih(const float* __restrict__ x,
        const float* __restrict__ Ain, const float* __restrict__ Bt,
        const float* __restrict__ hbuf0, float* __restrict__ yih) {
    __shared__ float xl[I_];
    __shared__ float u[NR_];
    __shared__ float v[NR_];
    int tb = blockIdx.x;
    int tid = threadIdx.x;
    xl[tid] = x[(size_t)tb * I_ + tid];
    xl[tid + 256] = x[(size_t)tb * I_ + tid + 256];
    __syncthreads();
    if (tid < NR_) {
        float a = 0.f;
        for (int jj = 0; jj < I_; ++jj) a += Ain[(size_t)jj * I_ + tid] * xl[jj];
        u[tid] = a;
    }
    __syncthreads();
    if (tid < NR_) {
        int k = tid;
        int start = k * NR_ - (k * (k - 1)) / 2;
        int cnt = NR_ - k;
        const float* cf = hbuf0 + (size_t)tb * NC_;
        float a = 0.f;
        for (int m = 0; m < cnt; ++m) a += cf[start + m] * u[cnt - 1 - m];
        v[k] = a;
    }
    __syncthreads();
    for (int h = tid; h < H_; h += 256) {
        float a = 0.f;
        #pragma unroll
        for (int k = 0; k < NR_; ++k) a += Bt[(size_t)k * H_ + h] * v[k];
        yih[(size_t)tb * H_ + h] = a;
    }
}

// sequential phase-2 (round-5 verified, ~108 us): Bt in LDS pitch 520, b128-aligned
#define BTP_ 520
__global__ __launch_bounds__(576) void k_seq(const float* __restrict__ yih,
        const float* __restrict__ Bt, const float* __restrict__ cf_all,
        const float* __restrict__ bias, float* __restrict__ out) {
    __shared__ __align__(16) float bt[NR_ * BTP_];   // 147.7 KB
    __shared__ __align__(16) float hl[H_];
    __shared__ float u[NR_ + 1];
    __shared__ __align__(16) float v[NR_ + 1];
    const int b = blockIdx.x, tid = threadIdx.x;
    for (int i = tid; i < NR_ * H_; i += 576)
        bt[(i >> 9) * BTP_ + (i & 511)] = Bt[i];
    for (int i = tid; i < H_; i += 576) hl[i] = 0.f;
    if (tid == 0) { u[NR_] = 0.f; v[NR_] = 0.f; }
    const float bv = (tid < H_) ? bias[tid] : 0.f;
    const int g = tid >> 3, lane = tid & 7;
    int start = 0, cnt = 0;
    if (g < NR_) { start = g * NR_ - (g * (g - 1)) / 2; cnt = NR_ - g; }
    __syncthreads();
    for (int t = 0; t < T_; ++t) {
        float cfv[9];
        if (g < NR_) {
            const float* cf = cf_all + ((size_t)t * B_ + b) * NC_ + start;
            #pragma unroll
            for (int mi = 0; mi < 9; ++mi) {
                int m = mi * 8 + lane;
                cfv[mi] = cf[m < cnt ? m : (cnt - 1)];
            }
        }
        if (g < NR_) {
            const float* bp = bt + g * BTP_ + lane * 4;
            const float* hp = hl + lane * 4;
            float a = 0.f;
            #pragma unroll
            for (int m = 0; m < 16; ++m) {
                float4 bq = *(const float4*)(bp + m * 32);
                float4 hq = *(const float4*)(hp + m * 32);
                a += bq.x * hq.x + bq.y * hq.y + bq.z * hq.z + bq.w * hq.w;
            }
            a += __shfl_xor(a, 1); a += __shfl_xor(a, 2); a += __shfl_xor(a, 4);
            if (lane == 0) u[g] = a;
        }
        __syncthreads();
        if (g < NR_) {
            float a = 0.f;
            #pragma unroll
            for (int mi = 0; mi < 9; ++mi) {
                int m = mi * 8 + lane;
                a += (m < cnt) ? cfv[mi] * u[cnt - 1 - m] : 0.f;
            }
            a += __shfl_xor(a, 1); a += __shfl_xor(a, 2); a += __shfl_xor(a, 4);
            if (lane == 0) v[g] = a;
        }
        __syncthreads();
        float hv = 0.f;
        if (tid < H_) {
            float4 vv[18];
            #pragma unroll
            for (int q = 0; q < 18; ++q) vv[q] = *(const float4*)(v + q * 4);
            float a0 = 0.f, a1 = 0.f;
            #pragma unroll
            for (int k = 0; k < NR_; ++k) {
                float vk = ((const float*)vv)[k];
                ((k & 1) ? a1 : a0) += bt[k * BTP_ + tid] * vk;
            }
            hv = tanhf(yih[((size_t)t * B_ + b) * H_ + tid] + a0 + a1 + bv);
            out[((size_t)t * B_ + b) * H_ + tid] = hv;
        }
        __syncthreads();
        if (tid < H_) hl[tid] = hv;
        __syncthreads();
    }
}

extern "C" void kernel_launch(void* const* d_in, const int* in_sizes, int n_in,
                              void* d_out, int out_size, void* d_ws, size_t ws_size,
                              hipStream_t stream) {
    const float* x        = (const float*)d_in[0];
    const float* wih_ih   = (const float*)d_in[1];
    const float* wih_hh   = (const float*)d_in[2];
    const float* wih_b    = (const float*)d_in[3];
    const float* whh_ih   = (const float*)d_in[4];
    const float* whh_hh   = (const float*)d_in[5];
    const float* whh_b    = (const float*)d_in[6];
    const float* scal_ih  = (const float*)d_in[7];
    const float* scal_hh  = (const float*)d_in[8];
    const float* bias     = (const float*)d_in[9];
    const float* idct_in  = (const float*)d_in[10];
    const float* idct_hid = (const float*)d_in[11];
    float* out = (float*)d_out;

    const size_t WP8_B  = (size_t)2 * NPR_ * NCP_;        //  52,428,800 (int8)
    const size_t SW_B   = (size_t)2 * NPR_ * 4;           //      81,920
    const size_t PRET_B = (size_t)2 * NPR_ * 512 * 2;     //  20,971,520
    const size_t HBUF_B = (size_t)2 * T_ * B_ * NC_ * 4;  //  10,469,376
    const size_t HBF_B  = (size_t)2 * 2 * B_ * NCP_ * 2;  //     327,680
    const size_t BAR_B  = 256;
    const size_t YIH_B  = (size_t)T_ * B_ * H_ * 4;
    const size_t BT_B   = (size_t)NR_ * H_ * 4;
    const size_t need = WP8_B + SW_B + PRET_B + HBUF_B + HBF_B + BAR_B + YIH_B + BT_B + 4096;

    char* ws = (char*)d_ws;
    size_t off = 0;
    auto alloc = [&](size_t bytes) -> void* {
        void* p = (void*)(ws + off);
        off += (bytes + 255) & ~(size_t)255;
        return p;
    };

    if (ws_size < need) return;   // harness workspace has always been >160MB

    signed char* Wp8 = (signed char*)alloc(WP8_B);
    float*  sW   = (float*)alloc(SW_B);
    ushort* preT = (ushort*)alloc(PRET_B);
    float*  hbuf = (float*)alloc(HBUF_B);
    ushort* hbf  = (ushort*)alloc(HBF_B);
    uint*   bar  = (uint*)alloc(BAR_B);
    float*  yih  = (float*)alloc(YIH_B);
    float*  Bt   = (float*)alloc(BT_B);
    // aliases inside Wp8 region (dead before k_cvt_whh_i8 runs)
    ushort* Wih_p = (ushort*)Wp8;                      // 21.0 MB
    ushort* Xbf   = (ushort*)((char*)Wp8 + 21000192);  // +0.5 MB, < 52.4 MB

    {   // zero hbf (ping-pong, incl. K-pad) + barrier counter (contiguous allocs)
        int n = (int)((HBF_B + BAR_B) / 4);
        hipLaunchKernelGGL(k_zero, dim3((n + 255) / 256), dim3(256), 0, stream,
                           (float*)hbf, n);
    }
    hipLaunchKernelGGL(k_cvt_x, dim3(256), dim3(256), 0, stream, x, Xbf);
    hipLaunchKernelGGL(k_cvt_w512p, dim3(NPR_ * 128 / 256, 1, 2), dim3(256), 0, stream,
                       wih_ih, whh_ih, Wih_p);
    hipLaunchKernelGGL(k_gih_mfma, dim3(160, 1, 2), dim3(256), 0, stream,
                       Xbf, Wih_p, wih_b, whh_b, preT);
    hipLaunchKernelGGL(k_cvt_whh_i8, dim3(NPR_ / 4, 1, 2), dim3(256), 0, stream,
                       wih_hh, whh_hh, Wp8, sW);

    hipLaunchKernelGGL(k_loop_p, dim3(PBLK_), dim3(256), 0, stream,
                       Wp8, sW, preT, hbf, hbuf, scal_ih, scal_hh, bar);

    hipLaunchKernelGGL(k_bt, dim3((NR_ * H_ + 255) / 256), dim3(256), 0, stream,
                       idct_hid, Bt);
    hipLaunchKernelGGL(k_yih, dim3(T_ * B_), dim3(256), 0, stream,
                       x, idct_in, Bt, hbuf, yih);
    hipLaunchKernelGGL(k_seq, dim3(B_), dim3(576), 0, stream,
                       yih, Bt, hbuf + (size_t)T_ * B_ * NC_, bias, out);
}

// Round 12
// 729.308 us; speedup vs baseline: 10.4022x; 10.4022x over previous
//
#include <hip/hip_runtime.h>
#include <hip/hip_bf16.h>

#define T_ 32
#define B_ 16
#define I_ 512
#define H_ 512
#define OFF_ 441
#define NR_ 71           // I_ - OFF_
#define NC_ 2556         // NR_*(NR_+1)/2
#define G4_ (4*NC_)      // 10224
#define NCP_ 2560        // K padded
#define NPR_ 10240       // padded gate-permuted row count
#define NTIL_ 640        // NPR_/16

typedef __attribute__((ext_vector_type(8))) short bf16x8;
typedef __attribute__((ext_vector_type(4))) float f32x4;

__device__ __forceinline__ ushort bfc(float f) {
    __hip_bfloat16 h = __float2bfloat16(f);
    return *(ushort*)&h;
}
__device__ __forceinline__ float b2f(ushort u) {
    return __uint_as_float((uint)u << 16);
}
__device__ __forceinline__ float sigf(float x) { return 1.f / (1.f + expf(-x)); }

// int8x8 (two uints) -> integer-valued bf16x8 (exact for |v|<=127)
__device__ __forceinline__ bf16x8 dq8(uint lo, uint hi) {
    union { bf16x8 v; ushort us[8]; } r;
    #pragma unroll
    for (int i = 0; i < 4; ++i) {
        int b0 = (int)(signed char)(lo >> (8 * i));
        int b1 = (int)(signed char)(hi >> (8 * i));
        r.us[i]     = (ushort)(__float_as_uint((float)b0) >> 16);
        r.us[i + 4] = (ushort)(__float_as_uint((float)b1) >> 16);
    }
    return r.v;
}

__global__ void k_zero(float* __restrict__ p, int n) {
    int i = blockIdx.x * 256 + threadIdx.x;
    if (i < n) p[i] = 0.f;
}

// x fp32 [512][512] -> bf16 same layout
__global__ void k_cvt_x(const float* __restrict__ x, ushort* __restrict__ xb) {
    int i = blockIdx.x * 256 + threadIdx.x;
    float4 v = ((const float4*)x)[i];
    ushort4 o; o.x = bfc(v.x); o.y = bfc(v.y); o.z = bfc(v.z); o.w = bfc(v.w);
    ((ushort4*)xb)[i] = o;
}

// Wih[l] fp32 [G4][512] -> bf16 gate-permuted [NPR][512]; row n' = 4*jc+q <- q*NC+jc
__global__ void k_cvt_w512p(const float* __restrict__ W0, const float* __restrict__ W1,
                            ushort* __restrict__ dst) {
    int l = blockIdx.z;
    const float* src = l ? W1 : W0;
    size_t idx = (size_t)blockIdx.x * 256 + threadIdx.x;
    int np = (int)(idx >> 7), kq = (int)(idx & 127);
    ushort4 o; o.x = 0; o.y = 0; o.z = 0; o.w = 0;
    int jc = np >> 2, q = np & 3;
    if (jc < NC_) {
        float4 v = *(const float4*)(src + ((size_t)q * NC_ + jc) * I_ + kq * 4);
        o.x = bfc(v.x); o.y = bfc(v.y); o.z = bfc(v.z); o.w = bfc(v.w);
    }
    ((ushort4*)(dst + ((size_t)l * NPR_ + np) * I_))[kq] = o;
}

// Whh[l] fp32 [G4][2556] -> int8, k-interleaved MFMA-fragment layout:
// Wq8[l][tile nt][ks 0..79][lane 0..63][8], lane = kgrp*16 + row (row = np&15).
// Per-row scale in sW[l][np]. One wave per output row.
__global__ __launch_bounds__(256) void k_cvt_whh_i8(const float* __restrict__ W0,
        const float* __restrict__ W1,
        signed char* __restrict__ dst, float* __restrict__ sW) {
    const int l = blockIdx.z;
    const float* src = l ? W1 : W0;
    const int np = blockIdx.x * 4 + (threadIdx.x >> 6);
    const int lane = threadIdx.x & 63;
    const int jc = np >> 2, q = np & 3;
    float w[40];
    float mx = 0.f;
    if (jc < NC_) {
        const float* row = src + ((size_t)q * NC_ + jc) * NC_;
        #pragma unroll
        for (int i = 0; i < 40; ++i) {
            int k = lane + i * 64;
            w[i] = (k < NC_) ? row[k] : 0.f;
            mx = fmaxf(mx, fabsf(w[i]));
        }
    } else {
        #pragma unroll
        for (int i = 0; i < 40; ++i) w[i] = 0.f;
    }
    #pragma unroll
    for (int d = 1; d < 64; d <<= 1) mx = fmaxf(mx, __shfl_xor(mx, d));
    const float inv = (mx > 0.f) ? 127.f / mx : 0.f;
    const int nt = np >> 4, r = np & 15;
    signed char* obase = dst + (((size_t)l * NTIL_ + nt) * 80) * 512;
    #pragma unroll
    for (int i = 0; i < 40; ++i) {
        int k = lane + i * 64;
        int ks = k >> 5, kgrp = (k >> 3) & 3, e = k & 7;
        obase[(size_t)ks * 512 + (kgrp * 16 + r) * 8 + e] =
            (signed char)(int)rintf(w[i] * inv);
    }
    if (lane == 0) sW[(size_t)l * NPR_ + np] = (mx > 0.f) ? mx / 127.f : 0.f;
}

// MFMA input GEMM -> preT[l][n'][m] bf16, m = t*16+b; permuted bias added
__global__ __launch_bounds__(256) void k_gih_mfma(const ushort* __restrict__ Xbf,
        const ushort* __restrict__ Wp,
        const float* __restrict__ b0, const float* __restrict__ b1,
        ushort* __restrict__ preT) {
    const int l = blockIdx.z;
    const float* bb = l ? b1 : b0;
    const int wid = threadIdx.x >> 6, lane = threadIdx.x & 63;
    const int nt = blockIdx.x * 4 + wid;
    __shared__ ushort lds_a[32 * 64 * 8];
    const int srow = lane & 15, skq = (lane >> 4) * 8;
    const ushort* wp = Wp + ((size_t)l * NPR_ + nt * 16 + srow) * I_ + skq;
    f32x4 acc[32];
    #pragma unroll
    for (int mt = 0; mt < 32; ++mt) acc[mt] = (f32x4){0.f, 0.f, 0.f, 0.f};
    for (int ks = 0; ks < 16; ++ks) {
        #pragma unroll
        for (int i = 0; i < 8; ++i) {
            int mt = wid * 8 + i;
            bf16x8 xv = *(const bf16x8*)(Xbf + (size_t)(mt * 16 + srow) * I_ + ks * 32 + skq);
            *(bf16x8*)(lds_a + (mt * 64 + lane) * 8) = xv;
        }
        bf16x8 b = *(const bf16x8*)(wp + ks * 32);
        __syncthreads();
        #pragma unroll
        for (int mt = 0; mt < 32; ++mt) {
            bf16x8 a = *(const bf16x8*)(lds_a + (mt * 64 + lane) * 8);
            acc[mt] = __builtin_amdgcn_mfma_f32_16x16x32_bf16(a, b, acc[mt], 0, 0, 0);
        }
        __syncthreads();
    }
    const int n = nt * 16 + srow;
    const float bv = (n < G4_) ? bb[(size_t)(n & 3) * NC_ + (n >> 2)] : 0.f;
    const int r0 = (lane >> 4) * 4;
    ushort* po = preT + ((size_t)l * NPR_ + n) * 512;
    #pragma unroll
    for (int mt = 0; mt < 32; ++mt) {
        ushort4 o;
        o.x = bfc(acc[mt][0] + bv); o.y = bfc(acc[mt][1] + bv);
        o.z = bfc(acc[mt][2] + bv); o.w = bfc(acc[mt][3] + bv);
        *(ushort4*)(po + mt * 16 + r0) = o;
    }
}

// Fused recurrent step v3: coalesced k-interleaved W (512B/wave-load) and
// h (1KB/wave-load); 4 waves/block, K split 4x640; preT/sW prefetched.
// h layout per pp/layer: hq[ks 0..79][kgrp*16+batch][8] bf16 (40960 ushorts/layer).
__global__ __launch_bounds__(256, 4) void k_step(const signed char* __restrict__ Wq8,
        const float* __restrict__ sW, const ushort* __restrict__ preT,
        const ushort* __restrict__ hq_in, ushort* __restrict__ hq_out,
        float* __restrict__ cst, float* __restrict__ hbuf,
        const float* __restrict__ scal_ih, const float* __restrict__ scal_hh,
        int t) {
    const int l = blockIdx.z;
    const int nt = blockIdx.x;
    const int tid = threadIdx.x;
    const int w = tid >> 6, lane = tid & 63;
    // prefetch gate operands early (hidden under MFMA phase)
    float pv[4], swv[4];
    const int b_g = tid & 15, jq_g = tid >> 4;      // valid for tid<64
    const int jc_g = nt * 4 + jq_g;
    if (tid < 64) {
        #pragma unroll
        for (int q = 0; q < 4; ++q) {
            const int row = nt * 16 + jq_g * 4 + q;
            pv[q]  = b2f(preT[((size_t)l * NPR_ + row) * 512 + t * 16 + b_g]);
            swv[q] = sW[(size_t)l * NPR_ + row];
        }
    }
    const signed char* wp = Wq8 + ((((size_t)l * NTIL_ + nt) * 80 + w * 20) << 9) + lane * 8;
    const ushort* hp = hq_in + (size_t)l * 40960 + (w * 20) * 512 + lane * 8;
    f32x4 acc = {0.f, 0.f, 0.f, 0.f};
    #pragma unroll 5
    for (int ks = 0; ks < 20; ++ks) {
        uint2 wb = *(const uint2*)(wp + ks * 512);
        bf16x8 a = *(const bf16x8*)(hp + ks * 512);
        acc = __builtin_amdgcn_mfma_f32_16x16x32_bf16(a, dq8(wb.x, wb.y), acc, 0, 0, 0);
    }
    __shared__ float gl[4][16][17];
    const int col = lane & 15;
    const int m0 = (lane >> 4) * 4;
    gl[w][col][m0 + 0] = acc[0];
    gl[w][col][m0 + 1] = acc[1];
    gl[w][col][m0 + 2] = acc[2];
    gl[w][col][m0 + 3] = acc[3];
    __syncthreads();
    // gate pass on first wave: thread -> (b = tid&15, jq = tid>>4)
    if (tid < 64 && jc_g < NC_) {
        float g[4];
        #pragma unroll
        for (int q = 0; q < 4; ++q) {
            float s = gl[0][jq_g * 4 + q][b_g] + gl[1][jq_g * 4 + q][b_g]
                    + gl[2][jq_g * 4 + q][b_g] + gl[3][jq_g * 4 + q][b_g];
            g[q] = s * swv[q] + pv[q];
        }
        float* cp = cst + ((size_t)l * NC_ + jc_g) * B_ + b_g;
        float ci = *cp;
        float cn = sigf(g[1]) * ci + sigf(g[0]) * tanhf(g[2]);
        float hn = sigf(g[3]) * tanhf(cn);
        *cp = cn;
        const int ks = jc_g >> 5, kgrp = (jc_g >> 3) & 3, e = jc_g & 7;
        hq_out[(size_t)l * 40960 + (size_t)ks * 512 + (kgrp * 16 + b_g) * 8 + e] = bfc(hn);
        float sc = (l ? scal_hh : scal_ih)[jc_g];
        hbuf[(((size_t)l * T_ + t) * B_ + b_g) * NC_ + jc_g] = hn * sc;
    }
}

// Bt[k][h] = idct_hid[h][k] for k < 71
__global__ void k_bt(const float* __restrict__ Bh, float* __restrict__ Bt) {
    int idx = blockIdx.x * 256 + threadIdx.x;
    if (idx < NR_ * H_) {
        int k = idx / H_, h = idx - k * H_;
        Bt[idx] = Bh[(size_t)h * H_ + k];
    }
}

// yih[t,b,h] = sum_k Bt[k,h] * v[k]; coeffs pre-scaled in hbuf
__global__ __launch_bounds__(256) void k_yih(const float* __restrict__ x,
        const float* __restrict__ Ain, const float* __restrict__ Bt,
        const float* __restrict__ hbuf0, float* __restrict__ yih) {
    __shared__ float xl[I_];
    __shared__ float u[NR_];
    __shared__ float v[NR_];
    int tb = blockIdx.x;
    int tid = threadIdx.x;
    xl[tid] = x[(size_t)tb * I_ + tid];
    xl[tid + 256] = x[(size_t)tb * I_ + tid + 256];
    __syncthreads();
    if (tid < NR_) {
        float a = 0.f;
        for (int jj = 0; jj < I_; ++jj) a += Ain[(size_t)jj * I_ + tid] * xl[jj];
        u[tid] = a;
    }
    __syncthreads();
    if (tid < NR_) {
        int k = tid;
        int start = k * NR_ - (k * (k - 1)) / 2;
        int cnt = NR_ - k;
        const float* cf = hbuf0 + (size_t)tb * NC_;
        float a = 0.f;
        for (int m = 0; m < cnt; ++m) a += cf[start + m] * u[cnt - 1 - m];
        v[k] = a;
    }
    __syncthreads();
    for (int h = tid; h < H_; h += 256) {
        float a = 0.f;
        #pragma unroll
        for (int k = 0; k < NR_; ++k) a += Bt[(size_t)k * H_ + h] * v[k];
        yih[(size_t)tb * H_ + h] = a;
    }
}

// sequential phase-2 (round-5 verified, ~108 us): Bt in LDS pitch 520, b128-aligned
#define BTP_ 520
__global__ __launch_bounds__(576) void k_seq(const float* __restrict__ yih,
        const float* __restrict__ Bt, const float* __restrict__ cf_all,
        const float* __restrict__ bias, float* __restrict__ out) {
    __shared__ __align__(16) float bt[NR_ * BTP_];   // 147.7 KB
    __shared__ __align__(16) float hl[H_];
    __shared__ float u[NR_ + 1];
    __shared__ __align__(16) float v[NR_ + 1];
    const int b = blockIdx.x, tid = threadIdx.x;
    for (int i = tid; i < NR_ * H_; i += 576)
        bt[(i >> 9) * BTP_ + (i & 511)] = Bt[i];
    for (int i = tid; i < H_; i += 576) hl[i] = 0.f;
    if (tid == 0) { u[NR_] = 0.f; v[NR_] = 0.f; }
    const float bv = (tid < H_) ? bias[tid] : 0.f;
    const int g = tid >> 3, lane = tid & 7;
    int start = 0, cnt = 0;
    if (g < NR_) { start = g * NR_ - (g * (g - 1)) / 2; cnt = NR_ - g; }
    __syncthreads();
    for (int t = 0; t < T_; ++t) {
        float cfv[9];
        if (g < NR_) {
            const float* cf = cf_all + ((size_t)t * B_ + b) * NC_ + start;
            #pragma unroll
            for (int mi = 0; mi < 9; ++mi) {
                int m = mi * 8 + lane;
                cfv[mi] = cf[m < cnt ? m : (cnt - 1)];
            }
        }
        if (g < NR_) {
            const float* bp = bt + g * BTP_ + lane * 4;
            const float* hp = hl + lane * 4;
            float a = 0.f;
            #pragma unroll
            for (int m = 0; m < 16; ++m) {
                float4 bq = *(const float4*)(bp + m * 32);
                float4 hq = *(const float4*)(hp + m * 32);
                a += bq.x * hq.x + bq.y * hq.y + bq.z * hq.z + bq.w * hq.w;
            }
            a += __shfl_xor(a, 1); a += __shfl_xor(a, 2); a += __shfl_xor(a, 4);
            if (lane == 0) u[g] = a;
        }
        __syncthreads();
        if (g < NR_) {
            float a = 0.f;
            #pragma unroll
            for (int mi = 0; mi < 9; ++mi) {
                int m = mi * 8 + lane;
                a += (m < cnt) ? cfv[mi] * u[cnt - 1 - m] : 0.f;
            }
            a += __shfl_xor(a, 1); a += __shfl_xor(a, 2); a += __shfl_xor(a, 4);
            if (lane == 0) v[g] = a;
        }
        __syncthreads();
        float hv = 0.f;
        if (tid < H_) {
            float4 vv[18];
            #pragma unroll
            for (int q = 0; q < 18; ++q) vv[q] = *(const float4*)(v + q * 4);
            float a0 = 0.f, a1 = 0.f;
            #pragma unroll
            for (int k = 0; k < NR_; ++k) {
                float vk = ((const float*)vv)[k];
                ((k & 1) ? a1 : a0) += bt[k * BTP_ + tid] * vk;
            }
            hv = tanhf(yih[((size_t)t * B_ + b) * H_ + tid] + a0 + a1 + bv);
            out[((size_t)t * B_ + b) * H_ + tid] = hv;
        }
        __syncthreads();
        if (tid < H_) hl[tid] = hv;
        __syncthreads();
    }
}

extern "C" void kernel_launch(void* const* d_in, const int* in_sizes, int n_in,
                              void* d_out, int out_size, void* d_ws, size_t ws_size,
                              hipStream_t stream) {
    const float* x        = (const float*)d_in[0];
    const float* wih_ih   = (const float*)d_in[1];
    const float* wih_hh   = (const float*)d_in[2];
    const float* wih_b    = (const float*)d_in[3];
    const float* whh_ih   = (const float*)d_in[4];
    const float* whh_hh   = (const float*)d_in[5];
    const float* whh_b    = (const float*)d_in[6];
    const float* scal_ih  = (const float*)d_in[7];
    const float* scal_hh  = (const float*)d_in[8];
    const float* bias     = (const float*)d_in[9];
    const float* idct_in  = (const float*)d_in[10];
    const float* idct_hid = (const float*)d_in[11];
    float* out = (float*)d_out;

    const size_t WP8_B  = (size_t)2 * NPR_ * NCP_;        //  52,428,800 (int8, k-interleaved)
    const size_t SW_B   = (size_t)2 * NPR_ * 4;           //      81,920
    const size_t PRET_B = (size_t)2 * NPR_ * 512 * 2;     //  20,971,520
    const size_t HBUF_B = (size_t)2 * T_ * B_ * NC_ * 4;  //  10,469,376
    const size_t HBF_B  = (size_t)2 * 2 * B_ * NCP_ * 2;  //     327,680 (pp x layer, k-interleaved)
    const size_t CST_B  = (size_t)2 * NC_ * B_ * 4;       //     327,168
    const size_t YIH_B  = (size_t)T_ * B_ * H_ * 4;
    const size_t BT_B   = (size_t)NR_ * H_ * 4;
    const size_t need = WP8_B + SW_B + PRET_B + HBUF_B + HBF_B + CST_B + YIH_B + BT_B + 4096;

    char* ws = (char*)d_ws;
    size_t off = 0;
    auto alloc = [&](size_t bytes) -> void* {
        void* p = (void*)(ws + off);
        off += (bytes + 255) & ~(size_t)255;
        return p;
    };

    if (ws_size < need) return;   // harness workspace has always been >160MB

    signed char* Wp8 = (signed char*)alloc(WP8_B);
    float*  sW   = (float*)alloc(SW_B);
    ushort* preT = (ushort*)alloc(PRET_B);
    float*  hbuf = (float*)alloc(HBUF_B);
    ushort* hbf  = (ushort*)alloc(HBF_B);
    float*  cst  = (float*)alloc(CST_B);
    float*  yih  = (float*)alloc(YIH_B);
    float*  Bt   = (float*)alloc(BT_B);
    // aliases inside Wp8 region (dead before k_cvt_whh_i8 runs)
    ushort* Wih_p = (ushort*)Wp8;                      // 21.0 MB
    ushort* Xbf   = (ushort*)((char*)Wp8 + 21000192);  // +0.5 MB, < 52.4 MB

    {   // zero hbf (ping-pong, incl. K-pad) + cst (contiguous allocs)
        int n = (int)((HBF_B + CST_B) / 4);
        hipLaunchKernelGGL(k_zero, dim3((n + 255) / 256), dim3(256), 0, stream,
                           (float*)hbf, n);
    }
    hipLaunchKernelGGL(k_cvt_x, dim3(256), dim3(256), 0, stream, x, Xbf);
    hipLaunchKernelGGL(k_cvt_w512p, dim3(NPR_ * 128 / 256, 1, 2), dim3(256), 0, stream,
                       wih_ih, whh_ih, Wih_p);
    hipLaunchKernelGGL(k_gih_mfma, dim3(160, 1, 2), dim3(256), 0, stream,
                       Xbf, Wih_p, wih_b, whh_b, preT);
    hipLaunchKernelGGL(k_cvt_whh_i8, dim3(NPR_ / 4, 1, 2), dim3(256), 0, stream,
                       wih_hh, whh_hh, Wp8, sW);

    const size_t HS = (size_t)2 * B_ * NCP_;   // ushorts per ping-pong buffer (81920)
    for (int t = 0; t < T_; ++t) {
        const ushort* hin  = hbf + (size_t)(t & 1) * HS;
        ushort*       hout = hbf + (size_t)((t & 1) ^ 1) * HS;
        hipLaunchKernelGGL(k_step, dim3(NTIL_, 1, 2), dim3(256), 0, stream,
                           Wp8, sW, preT, hin, hout, cst, hbuf, scal_ih, scal_hh, t);
    }

    hipLaunchKernelGGL(k_bt, dim3((NR_ * H_ + 255) / 256), dim3(256), 0, stream,
                       idct_hid, Bt);
    hipLaunchKernelGGL(k_yih, dim3(T_ * B_), dim3(256), 0, stream,
                       x, idct_in, Bt, hbuf, yih);
    hipLaunchKernelGGL(k_seq, dim3(B_), dim3(576), 0, stream,
                       yih, Bt, hbuf + (size_t)T_ * B_ * NC_, bias, out);
}

// Round 13
// 712.291 us; speedup vs baseline: 10.6507x; 1.0239x over previous
//
#include <hip/hip_runtime.h>
#include <hip/hip_bf16.h>

#define T_ 32
#define B_ 16
#define I_ 512
#define H_ 512
#define OFF_ 441
#define NR_ 71           // I_ - OFF_
#define NC_ 2556         // NR_*(NR_+1)/2
#define G4_ (4*NC_)      // 10224
#define NCP_ 2560        // K padded
#define NPR_ 10240       // padded gate-permuted row count
#define NTIL_ 640        // NPR_/16

typedef __attribute__((ext_vector_type(8))) short bf16x8;
typedef __attribute__((ext_vector_type(4))) float f32x4;

__device__ __forceinline__ ushort bfc(float f) {
    __hip_bfloat16 h = __float2bfloat16(f);
    return *(ushort*)&h;
}
__device__ __forceinline__ float b2f(ushort u) {
    return __uint_as_float((uint)u << 16);
}
__device__ __forceinline__ float sigf(float x) { return 1.f / (1.f + expf(-x)); }

// int8x8 (two uints) -> integer-valued bf16x8 (exact for |v|<=127)
__device__ __forceinline__ bf16x8 dq8(uint lo, uint hi) {
    union { bf16x8 v; ushort us[8]; } r;
    #pragma unroll
    for (int i = 0; i < 4; ++i) {
        int b0 = (int)(signed char)(lo >> (8 * i));
        int b1 = (int)(signed char)(hi >> (8 * i));
        r.us[i]     = (ushort)(__float_as_uint((float)b0) >> 16);
        r.us[i + 4] = (ushort)(__float_as_uint((float)b1) >> 16);
    }
    return r.v;
}

__global__ void k_zero(float* __restrict__ p, int n) {
    int i = blockIdx.x * 256 + threadIdx.x;
    if (i < n) p[i] = 0.f;
}

// x fp32 [512][512] -> bf16 same layout
__global__ void k_cvt_x(const float* __restrict__ x, ushort* __restrict__ xb) {
    int i = blockIdx.x * 256 + threadIdx.x;
    float4 v = ((const float4*)x)[i];
    ushort4 o; o.x = bfc(v.x); o.y = bfc(v.y); o.z = bfc(v.z); o.w = bfc(v.w);
    ((ushort4*)xb)[i] = o;
}

// Wih[l] fp32 [G4][512] -> bf16 gate-permuted [NPR][512]; row n' = 4*jc+q <- q*NC+jc
__global__ void k_cvt_w512p(const float* __restrict__ W0, const float* __restrict__ W1,
                            ushort* __restrict__ dst) {
    int l = blockIdx.z;
    const float* src = l ? W1 : W0;
    size_t idx = (size_t)blockIdx.x * 256 + threadIdx.x;
    int np = (int)(idx >> 7), kq = (int)(idx & 127);
    ushort4 o; o.x = 0; o.y = 0; o.z = 0; o.w = 0;
    int jc = np >> 2, q = np & 3;
    if (jc < NC_) {
        float4 v = *(const float4*)(src + ((size_t)q * NC_ + jc) * I_ + kq * 4);
        o.x = bfc(v.x); o.y = bfc(v.y); o.z = bfc(v.z); o.w = bfc(v.w);
    }
    ((ushort4*)(dst + ((size_t)l * NPR_ + np) * I_))[kq] = o;
}

// Whh[l] fp32 [G4][2556] -> int8, k-interleaved MFMA-fragment layout:
// Wq8[l][tile nt][ks 0..79][lane 0..63][8], lane = kgrp*16 + row (row = np&15).
// Per-row scale in sW[l][np]. One wave per output row; vectorized 8B stores.
__global__ __launch_bounds__(256) void k_cvt_whh_i8(const float* __restrict__ W0,
        const float* __restrict__ W1,
        signed char* __restrict__ dst, float* __restrict__ sW) {
    const int l = blockIdx.z;
    const float* src = l ? W1 : W0;
    const int np = blockIdx.x * 4 + (threadIdx.x >> 6);
    const int lane = threadIdx.x & 63;
    const int jc = np >> 2, q = np & 3;
    float w[40];
    float mx = 0.f;
    if (jc < NC_) {
        const float* row = src + ((size_t)q * NC_ + jc) * NC_;
        #pragma unroll
        for (int g = 0; g < 5; ++g) {
            int k0 = lane * 8 + g * 512;
            #pragma unroll
            for (int e = 0; e < 8; ++e) {
                int k = k0 + e;
                float v = (k < NC_) ? row[k] : 0.f;
                w[g * 8 + e] = v;
                mx = fmaxf(mx, fabsf(v));
            }
        }
    } else {
        #pragma unroll
        for (int i = 0; i < 40; ++i) w[i] = 0.f;
    }
    #pragma unroll
    for (int d = 1; d < 64; d <<= 1) mx = fmaxf(mx, __shfl_xor(mx, d));
    const float inv = (mx > 0.f) ? 127.f / mx : 0.f;
    const int nt = np >> 4, r = np & 15;
    signed char* obase = dst + (((size_t)l * NTIL_ + nt) * 80) * 512;
    #pragma unroll
    for (int g = 0; g < 5; ++g) {
        int k0 = lane * 8 + g * 512;
        int ks = k0 >> 5, kgrp = (k0 >> 3) & 3;
        uint lo = 0, hi = 0;
        #pragma unroll
        for (int e = 0; e < 4; ++e) {
            lo |= ((uint)(uchar)(signed char)(int)rintf(w[g * 8 + e] * inv)) << (8 * e);
            hi |= ((uint)(uchar)(signed char)(int)rintf(w[g * 8 + 4 + e] * inv)) << (8 * e);
        }
        *(uint2*)(obase + (size_t)ks * 512 + (kgrp * 16 + r) * 8) = make_uint2(lo, hi);
    }
    if (lane == 0) sW[(size_t)l * NPR_ + np] = (mx > 0.f) ? mx / 127.f : 0.f;
}

// MFMA input GEMM -> preT[l][n'][m] bf16, m = t*16+b; permuted bias added
__global__ __launch_bounds__(256) void k_gih_mfma(const ushort* __restrict__ Xbf,
        const ushort* __restrict__ Wp,
        const float* __restrict__ b0, const float* __restrict__ b1,
        ushort* __restrict__ preT) {
    const int l = blockIdx.z;
    const float* bb = l ? b1 : b0;
    const int wid = threadIdx.x >> 6, lane = threadIdx.x & 63;
    const int nt = blockIdx.x * 4 + wid;
    __shared__ ushort lds_a[32 * 64 * 8];
    const int srow = lane & 15, skq = (lane >> 4) * 8;
    const ushort* wp = Wp + ((size_t)l * NPR_ + nt * 16 + srow) * I_ + skq;
    f32x4 acc[32];
    #pragma unroll
    for (int mt = 0; mt < 32; ++mt) acc[mt] = (f32x4){0.f, 0.f, 0.f, 0.f};
    for (int ks = 0; ks < 16; ++ks) {
        #pragma unroll
        for (int i = 0; i < 8; ++i) {
            int mt = wid * 8 + i;
            bf16x8 xv = *(const bf16x8*)(Xbf + (size_t)(mt * 16 + srow) * I_ + ks * 32 + skq);
            *(bf16x8*)(lds_a + (mt * 64 + lane) * 8) = xv;
        }
        bf16x8 b = *(const bf16x8*)(wp + ks * 32);
        __syncthreads();
        #pragma unroll
        for (int mt = 0; mt < 32; ++mt) {
            bf16x8 a = *(const bf16x8*)(lds_a + (mt * 64 + lane) * 8);
            acc[mt] = __builtin_amdgcn_mfma_f32_16x16x32_bf16(a, b, acc[mt], 0, 0, 0);
        }
        __syncthreads();
    }
    const int n = nt * 16 + srow;
    const float bv = (n < G4_) ? bb[(size_t)(n & 3) * NC_ + (n >> 2)] : 0.f;
    const int r0 = (lane >> 4) * 4;
    ushort* po = preT + ((size_t)l * NPR_ + n) * 512;
    #pragma unroll
    for (int mt = 0; mt < 32; ++mt) {
        ushort4 o;
        o.x = bfc(acc[mt][0] + bv); o.y = bfc(acc[mt][1] + bv);
        o.z = bfc(acc[mt][2] + bv); o.w = bfc(acc[mt][3] + bv);
        *(ushort4*)(po + mt * 16 + r0) = o;
    }
}

// Fused recurrent step v4: 2 n-tiles per block (shared h load feeds 2 MFMAs),
// coalesced k-interleaved W (512B/wave-load) and h (1KB/wave-load);
// 4 waves/block over K quarters; preT/sW prefetched; grid (NTIL_/2, 1, 2).
__global__ __launch_bounds__(256, 4) void k_step(const signed char* __restrict__ Wq8,
        const float* __restrict__ sW, const ushort* __restrict__ preT,
        const ushort* __restrict__ hq_in, ushort* __restrict__ hq_out,
        float* __restrict__ cst, float* __restrict__ hbuf,
        const float* __restrict__ scal_ih, const float* __restrict__ scal_hh,
        int t) {
    const int l = blockIdx.z;
    const int nt0 = blockIdx.x * 2;
    const int tid = threadIdx.x;
    const int w = tid >> 6, lane = tid & 63;
    // prefetch gate operands early for both items (threads 0..127)
    float pv[4], swv[4];
    const int item_g = tid >> 6;                 // 0/1 for tid<128
    const int b_g = tid & 15, jq_g = (tid >> 4) & 3;
    const int nt_g = nt0 + item_g;
    const int jc_g = nt_g * 4 + jq_g;
    if (tid < 128) {
        #pragma unroll
        for (int q = 0; q < 4; ++q) {
            const int row = nt_g * 16 + jq_g * 4 + q;
            pv[q]  = b2f(preT[((size_t)l * NPR_ + row) * 512 + t * 16 + b_g]);
            swv[q] = sW[(size_t)l * NPR_ + row];
        }
    }
    const signed char* wp0 = Wq8 + ((((size_t)l * NTIL_ + nt0) * 80 + w * 20) << 9) + lane * 8;
    const signed char* wp1 = wp0 + ((size_t)80 << 9);      // next tile (+80*512 B)
    const ushort* hp = hq_in + (size_t)l * 40960 + (w * 20) * 512 + lane * 8;
    f32x4 acc0 = {0.f, 0.f, 0.f, 0.f};
    f32x4 acc1 = {0.f, 0.f, 0.f, 0.f};
    #pragma unroll 5
    for (int ks = 0; ks < 20; ++ks) {
        bf16x8 a = *(const bf16x8*)(hp + ks * 512);
        uint2 wb0 = *(const uint2*)(wp0 + ks * 512);
        uint2 wb1 = *(const uint2*)(wp1 + ks * 512);
        acc0 = __builtin_amdgcn_mfma_f32_16x16x32_bf16(a, dq8(wb0.x, wb0.y), acc0, 0, 0, 0);
        acc1 = __builtin_amdgcn_mfma_f32_16x16x32_bf16(a, dq8(wb1.x, wb1.y), acc1, 0, 0, 0);
    }
    __shared__ float gl[2][4][16][17];
    const int col = lane & 15;
    const int m0 = (lane >> 4) * 4;
    #pragma unroll
    for (int v = 0; v < 4; ++v) {
        gl[0][w][col][m0 + v] = acc0[v];
        gl[1][w][col][m0 + v] = acc1[v];
    }
    __syncthreads();
    // gate pass: threads 0..127, one (item, unit, batch) each
    if (tid < 128 && jc_g < NC_) {
        float g[4];
        #pragma unroll
        for (int q = 0; q < 4; ++q) {
            float s = gl[item_g][0][jq_g * 4 + q][b_g] + gl[item_g][1][jq_g * 4 + q][b_g]
                    + gl[item_g][2][jq_g * 4 + q][b_g] + gl[item_g][3][jq_g * 4 + q][b_g];
            g[q] = s * swv[q] + pv[q];
        }
        float* cp = cst + ((size_t)l * NC_ + jc_g) * B_ + b_g;
        float ci = *cp;
        float cn = sigf(g[1]) * ci + sigf(g[0]) * tanhf(g[2]);
        float hn = sigf(g[3]) * tanhf(cn);
        *cp = cn;
        const int ks = jc_g >> 5, kgrp = (jc_g >> 3) & 3, e = jc_g & 7;
        hq_out[(size_t)l * 40960 + (size_t)ks * 512 + (kgrp * 16 + b_g) * 8 + e] = bfc(hn);
        float sc = (l ? scal_hh : scal_ih)[jc_g];
        hbuf[(((size_t)l * T_ + t) * B_ + b_g) * NC_ + jc_g] = hn * sc;
    }
}

// Bt[k][h] = idct_hid[h][k] for k < 71
__global__ void k_bt(const float* __restrict__ Bh, float* __restrict__ Bt) {
    int idx = blockIdx.x * 256 + threadIdx.x;
    if (idx < NR_ * H_) {
        int k = idx / H_, h = idx - k * H_;
        Bt[idx] = Bh[(size_t)h * H_ + k];
    }
}

// yih[t,b,h] = sum_k Bt[k,h] * v[k]; coeffs pre-scaled in hbuf
__global__ __launch_bounds__(256) void k_yih(const float* __restrict__ x,
        const float* __restrict__ Ain, const float* __restrict__ Bt,
        const float* __restrict__ hbuf0, float* __restrict__ yih) {
    __shared__ float xl[I_];
    __shared__ float u[NR_];
    __shared__ float v[NR_];
    int tb = blockIdx.x;
    int tid = threadIdx.x;
    xl[tid] = x[(size_t)tb * I_ + tid];
    xl[tid + 256] = x[(size_t)tb * I_ + tid + 256];
    __syncthreads();
    if (tid < NR_) {
        float a = 0.f;
        for (int jj = 0; jj < I_; ++jj) a += Ain[(size_t)jj * I_ + tid] * xl[jj];
        u[tid] = a;
    }
    __syncthreads();
    if (tid < NR_) {
        int k = tid;
        int start = k * NR_ - (k * (k - 1)) / 2;
        int cnt = NR_ - k;
        const float* cf = hbuf0 + (size_t)tb * NC_;
        float a = 0.f;
        for (int m = 0; m < cnt; ++m) a += cf[start + m] * u[cnt - 1 - m];
        v[k] = a;
    }
    __syncthreads();
    for (int h = tid; h < H_; h += 256) {
        float a = 0.f;
        #pragma unroll
        for (int k = 0; k < NR_; ++k) a += Bt[(size_t)k * H_ + h] * v[k];
        yih[(size_t)tb * H_ + h] = a;
    }
}

// sequential phase-2 (round-5 verified, ~110 us): Bt in LDS pitch 520, b128-aligned
#define BTP_ 520
__global__ __launch_bounds__(576) void k_seq(const float* __restrict__ yih,
        const float* __restrict__ Bt, const float* __restrict__ cf_all,
        const float* __restrict__ bias, float* __restrict__ out) {
    __shared__ __align__(16) float bt[NR_ * BTP_];   // 147.7 KB
    __shared__ __align__(16) float hl[H_];
    __shared__ float u[NR_ + 1];
    __shared__ __align__(16) float v[NR_ + 1];
    const int b = blockIdx.x, tid = threadIdx.x;
    for (int i = tid; i < NR_ * H_; i += 576)
        bt[(i >> 9) * BTP_ + (i & 511)] = Bt[i];
    for (int i = tid; i < H_; i += 576) hl[i] = 0.f;
    if (tid == 0) { u[NR_] = 0.f; v[NR_] = 0.f; }
    const float bv = (tid < H_) ? bias[tid] : 0.f;
    const int g = tid >> 3, lane = tid & 7;
    int start = 0, cnt = 0;
    if (g < NR_) { start = g * NR_ - (g * (g - 1)) / 2; cnt = NR_ - g; }
    __syncthreads();
    for (int t = 0; t < T_; ++t) {
        float cfv[9];
        if (g < NR_) {
            const float* cf = cf_all + ((size_t)t * B_ + b) * NC_ + start;
            #pragma unroll
            for (int mi = 0; mi < 9; ++mi) {
                int m = mi * 8 + lane;
                cfv[mi] = cf[m < cnt ? m : (cnt - 1)];
            }
        }
        if (g < NR_) {
            const float* bp = bt + g * BTP_ + lane * 4;
            const float* hp = hl + lane * 4;
            float a = 0.f;
            #pragma unroll
            for (int m = 0; m < 16; ++m) {
                float4 bq = *(const float4*)(bp + m * 32);
                float4 hq = *(const float4*)(hp + m * 32);
                a += bq.x * hq.x + bq.y * hq.y + bq.z * hq.z + bq.w * hq.w;
            }
            a += __shfl_xor(a, 1); a += __shfl_xor(a, 2); a += __shfl_xor(a, 4);
            if (lane == 0) u[g] = a;
        }
        __syncthreads();
        if (g < NR_) {
            float a = 0.f;
            #pragma unroll
            for (int mi = 0; mi < 9; ++mi) {
                int m = mi * 8 + lane;
                a += (m < cnt) ? cfv[mi] * u[cnt - 1 - m] : 0.f;
            }
            a += __shfl_xor(a, 1); a += __shfl_xor(a, 2); a += __shfl_xor(a, 4);
            if (lane == 0) v[g] = a;
        }
        __syncthreads();
        float hv = 0.f;
        if (tid < H_) {
            float4 vv[18];
            #pragma unroll
            for (int q = 0; q < 18; ++q) vv[q] = *(const float4*)(v + q * 4);
            float a0 = 0.f, a1 = 0.f;
            #pragma unroll
            for (int k = 0; k < NR_; ++k) {
                float vk = ((const float*)vv)[k];
                ((k & 1) ? a1 : a0) += bt[k * BTP_ + tid] * vk;
            }
            hv = tanhf(yih[((size_t)t * B_ + b) * H_ + tid] + a0 + a1 + bv);
            out[((size_t)t * B_ + b) * H_ + tid] = hv;
        }
        __syncthreads();
        if (tid < H_) hl[tid] = hv;
        __syncthreads();
    }
}

extern "C" void kernel_launch(void* const* d_in, const int* in_sizes, int n_in,
                              void* d_out, int out_size, void* d_ws, size_t ws_size,
                              hipStream_t stream) {
    const float* x        = (const float*)d_in[0];
    const float* wih_ih   = (const float*)d_in[1];
    const float* wih_hh   = (const float*)d_in[2];
    const float* wih_b    = (const float*)d_in[3];
    const float* whh_ih   = (const float*)d_in[4];
    const float* whh_hh   = (const float*)d_in[5];
    const float* whh_b    = (const float*)d_in[6];
    const float* scal_ih  = (const float*)d_in[7];
    const float* scal_hh  = (const float*)d_in[8];
    const float* bias     = (const float*)d_in[9];
    const float* idct_in  = (const float*)d_in[10];
    const float* idct_hid = (const float*)d_in[11];
    float* out = (float*)d_out;

    const size_t WP8_B  = (size_t)2 * NPR_ * NCP_;        //  52,428,800 (int8, k-interleaved)
    const size_t SW_B   = (size_t)2 * NPR_ * 4;           //      81,920
    const size_t PRET_B = (size_t)2 * NPR_ * 512 * 2;     //  20,971,520
    const size_t HBUF_B = (size_t)2 * T_ * B_ * NC_ * 4;  //  10,469,376
    const size_t HBF_B  = (size_t)2 * 2 * B_ * NCP_ * 2;  //     327,680 (pp x layer, k-interleaved)
    const size_t CST_B  = (size_t)2 * NC_ * B_ * 4;       //     327,168
    const size_t YIH_B  = (size_t)T_ * B_ * H_ * 4;
    const size_t BT_B   = (size_t)NR_ * H_ * 4;
    const size_t need = WP8_B + SW_B + PRET_B + HBUF_B + HBF_B + CST_B + YIH_B + BT_B + 4096;

    char* ws = (char*)d_ws;
    size_t off = 0;
    auto alloc = [&](size_t bytes) -> void* {
        void* p = (void*)(ws + off);
        off += (bytes + 255) & ~(size_t)255;
        return p;
    };

    if (ws_size < need) return;   // harness workspace has always been >160MB

    signed char* Wp8 = (signed char*)alloc(WP8_B);
    float*  sW   = (float*)alloc(SW_B);
    ushort* preT = (ushort*)alloc(PRET_B);
    float*  hbuf = (float*)alloc(HBUF_B);
    ushort* hbf  = (ushort*)alloc(HBF_B);
    float*  cst  = (float*)alloc(CST_B);
    float*  yih  = (float*)alloc(YIH_B);
    float*  Bt   = (float*)alloc(BT_B);
    // aliases inside Wp8 region (dead before k_cvt_whh_i8 runs)
    ushort* Wih_p = (ushort*)Wp8;                      // 21.0 MB
    ushort* Xbf   = (ushort*)((char*)Wp8 + 21000192);  // +0.5 MB, < 52.4 MB

    {   // zero hbf (ping-pong, incl. K-pad) + cst (contiguous allocs)
        int n = (int)((HBF_B + CST_B) / 4);
        hipLaunchKernelGGL(k_zero, dim3((n + 255) / 256), dim3(256), 0, stream,
                           (float*)hbf, n);
    }
    hipLaunchKernelGGL(k_cvt_x, dim3(256), dim3(256), 0, stream, x, Xbf);
    hipLaunchKernelGGL(k_cvt_w512p, dim3(NPR_ * 128 / 256, 1, 2), dim3(256), 0, stream,
                       wih_ih, whh_ih, Wih_p);
    hipLaunchKernelGGL(k_gih_mfma, dim3(160, 1, 2), dim3(256), 0, stream,
                       Xbf, Wih_p, wih_b, whh_b, preT);
    hipLaunchKernelGGL(k_cvt_whh_i8, dim3(NPR_ / 4, 1, 2), dim3(256), 0, stream,
                       wih_hh, whh_hh, Wp8, sW);

    const size_t HS = (size_t)2 * B_ * NCP_;   // ushorts per ping-pong buffer (81920)
    for (int t = 0; t < T_; ++t) {
        const ushort* hin  = hbf + (size_t)(t & 1) * HS;
        ushort*       hout = hbf + (size_t)((t & 1) ^ 1) * HS;
        hipLaunchKernelGGL(k_step, dim3(NTIL_ / 2, 1, 2), dim3(256), 0, stream,
                           Wp8, sW, preT, hin, hout, cst, hbuf, scal_ih, scal_hh, t);
    }

    hipLaunchKernelGGL(k_bt, dim3((NR_ * H_ + 255) / 256), dim3(256), 0, stream,
                       idct_hid, Bt);
    hipLaunchKernelGGL(k_yih, dim3(T_ * B_), dim3(256), 0, stream,
                       x, idct_in, Bt, hbuf, yih);
    hipLaunchKernelGGL(k_seq, dim3(B_), dim3(576), 0, stream,
                       yih, Bt, hbuf + (size_t)T_ * B_ * NC_, bias, out);
}

// Round 14
// 680.032 us; speedup vs baseline: 11.1560x; 1.0474x over previous
//
#include <hip/hip_runtime.h>
#include <hip/hip_bf16.h>

#define T_ 32
#define B_ 16
#define I_ 512
#define H_ 512
#define OFF_ 441
#define NR_ 71           // I_ - OFF_
#define NC_ 2556         // NR_*(NR_+1)/2
#define G4_ (4*NC_)      // 10224
#define NCP_ 2560        // K padded
#define NPR_ 10240       // padded gate-permuted row count
#define NTIL_ 640        // NPR_/16

typedef __attribute__((ext_vector_type(8))) short bf16x8;
typedef __attribute__((ext_vector_type(4))) float f32x4;
typedef __attribute__((ext_vector_type(4))) int   i32x4;

__device__ __forceinline__ ushort bfc(float f) {
    __hip_bfloat16 h = __float2bfloat16(f);
    return *(ushort*)&h;
}
__device__ __forceinline__ float b2f(ushort u) {
    return __uint_as_float((uint)u << 16);
}
__device__ __forceinline__ float sigf(float x) { return 1.f / (1.f + expf(-x)); }

__global__ void k_zero(float* __restrict__ p, int n) {
    int i = blockIdx.x * 256 + threadIdx.x;
    if (i < n) p[i] = 0.f;
}

// x fp32 [512][512] -> bf16 same layout
__global__ void k_cvt_x(const float* __restrict__ x, ushort* __restrict__ xb) {
    int i = blockIdx.x * 256 + threadIdx.x;
    float4 v = ((const float4*)x)[i];
    ushort4 o; o.x = bfc(v.x); o.y = bfc(v.y); o.z = bfc(v.z); o.w = bfc(v.w);
    ((ushort4*)xb)[i] = o;
}

// Wih[l] fp32 [G4][512] -> bf16 gate-permuted [NPR][512]; row n' = 4*jc+q <- q*NC+jc
__global__ void k_cvt_w512p(const float* __restrict__ W0, const float* __restrict__ W1,
                            ushort* __restrict__ dst) {
    int l = blockIdx.z;
    const float* src = l ? W1 : W0;
    size_t idx = (size_t)blockIdx.x * 256 + threadIdx.x;
    int np = (int)(idx >> 7), kq = (int)(idx & 127);
    ushort4 o; o.x = 0; o.y = 0; o.z = 0; o.w = 0;
    int jc = np >> 2, q = np & 3;
    if (jc < NC_) {
        float4 v = *(const float4*)(src + ((size_t)q * NC_ + jc) * I_ + kq * 4);
        o.x = bfc(v.x); o.y = bfc(v.y); o.z = bfc(v.z); o.w = bfc(v.w);
    }
    ((ushort4*)(dst + ((size_t)l * NPR_ + np) * I_))[kq] = o;
}

// Whh[l] fp32 [G4][2556] -> int8, K=64-interleaved i8-MFMA fragment layout:
// Wq8[l][tile nt][ks 0..39][lane 0..63][16], lane = kgrp*16 + row, k = ks*64 + kgrp*16 + e.
// Per-row scale in sW[l][np]. One wave per output row; 8B vectorized stores.
__global__ __launch_bounds__(256) void k_cvt_whh_i8(const float* __restrict__ W0,
        const float* __restrict__ W1,
        signed char* __restrict__ dst, float* __restrict__ sW) {
    const int l = blockIdx.z;
    const float* src = l ? W1 : W0;
    const int np = blockIdx.x * 4 + (threadIdx.x >> 6);
    const int lane = threadIdx.x & 63;
    const int jc = np >> 2, q = np & 3;
    float w[40];
    float mx = 0.f;
    if (jc < NC_) {
        const float* row = src + ((size_t)q * NC_ + jc) * NC_;
        #pragma unroll
        for (int g = 0; g < 5; ++g) {
            int k0 = g * 512 + lane * 8;
            #pragma unroll
            for (int e = 0; e < 8; ++e) {
                int k = k0 + e;
                float v = (k < NC_) ? row[k] : 0.f;
                w[g * 8 + e] = v;
                mx = fmaxf(mx, fabsf(v));
            }
        }
    } else {
        #pragma unroll
        for (int i = 0; i < 40; ++i) w[i] = 0.f;
    }
    #pragma unroll
    for (int d = 1; d < 64; d <<= 1) mx = fmaxf(mx, __shfl_xor(mx, d));
    const float inv = (mx > 0.f) ? 127.f / mx : 0.f;
    const int nt = np >> 4, r = np & 15;
    signed char* obase = dst + (((size_t)l * NTIL_ + nt) * 40) * 1024;
    #pragma unroll
    for (int g = 0; g < 5; ++g) {
        int k0 = g * 512 + lane * 8;
        int ks = k0 >> 6, kgrp = (k0 >> 4) & 3, e = k0 & 15;   // e in {0,8}
        uint lo = 0, hi = 0;
        #pragma unroll
        for (int ee = 0; ee < 4; ++ee) {
            lo |= ((uint)(uchar)(signed char)(int)rintf(w[g * 8 + ee] * inv)) << (8 * ee);
            hi |= ((uint)(uchar)(signed char)(int)rintf(w[g * 8 + 4 + ee] * inv)) << (8 * ee);
        }
        *(uint2*)(obase + (size_t)ks * 1024 + (kgrp * 16 + r) * 16 + e) = make_uint2(lo, hi);
    }
    if (lane == 0) sW[(size_t)l * NPR_ + np] = (mx > 0.f) ? mx / 127.f : 0.f;
}

// MFMA input GEMM -> preT[l][n'][m] bf16, m = t*16+b; permuted bias added
__global__ __launch_bounds__(256) void k_gih_mfma(const ushort* __restrict__ Xbf,
        const ushort* __restrict__ Wp,
        const float* __restrict__ b0, const float* __restrict__ b1,
        ushort* __restrict__ preT) {
    const int l = blockIdx.z;
    const float* bb = l ? b1 : b0;
    const int wid = threadIdx.x >> 6, lane = threadIdx.x & 63;
    const int nt = blockIdx.x * 4 + wid;
    __shared__ ushort lds_a[32 * 64 * 8];
    const int srow = lane & 15, skq = (lane >> 4) * 8;
    const ushort* wp = Wp + ((size_t)l * NPR_ + nt * 16 + srow) * I_ + skq;
    f32x4 acc[32];
    #pragma unroll
    for (int mt = 0; mt < 32; ++mt) acc[mt] = (f32x4){0.f, 0.f, 0.f, 0.f};
    for (int ks = 0; ks < 16; ++ks) {
        #pragma unroll
        for (int i = 0; i < 8; ++i) {
            int mt = wid * 8 + i;
            bf16x8 xv = *(const bf16x8*)(Xbf + (size_t)(mt * 16 + srow) * I_ + ks * 32 + skq);
            *(bf16x8*)(lds_a + (mt * 64 + lane) * 8) = xv;
        }
        bf16x8 b = *(const bf16x8*)(wp + ks * 32);
        __syncthreads();
        #pragma unroll
        for (int mt = 0; mt < 32; ++mt) {
            bf16x8 a = *(const bf16x8*)(lds_a + (mt * 64 + lane) * 8);
            acc[mt] = __builtin_amdgcn_mfma_f32_16x16x32_bf16(a, b, acc[mt], 0, 0, 0);
        }
        __syncthreads();
    }
    const int n = nt * 16 + srow;
    const float bv = (n < G4_) ? bb[(size_t)(n & 3) * NC_ + (n >> 2)] : 0.f;
    const int r0 = (lane >> 4) * 4;
    ushort* po = preT + ((size_t)l * NPR_ + n) * 512;
    #pragma unroll
    for (int mt = 0; mt < 32; ++mt) {
        ushort4 o;
        o.x = bfc(acc[mt][0] + bv); o.y = bfc(acc[mt][1] + bv);
        o.z = bfc(acc[mt][2] + bv); o.w = bfc(acc[mt][3] + bv);
        *(ushort4*)(po + mt * 16 + r0) = o;
    }
}

// Fused recurrent step v5: native i8 MFMA (K=64), split-precision h (hi + lo/127),
// 2 n-tiles per block share h loads; no dequant VALU; grid (NTIL_/2, 1, 2).
// h layout per pp: [l][hi|lo][ks 0..39][kgrp*16+b][16] int8 (81920 B per layer).
__global__ __launch_bounds__(256, 4) void k_step(const signed char* __restrict__ Wq8,
        const float* __restrict__ sW, const ushort* __restrict__ preT,
        const signed char* __restrict__ h_in, signed char* __restrict__ h_out,
        float* __restrict__ cst, float* __restrict__ hbuf,
        const float* __restrict__ scal_ih, const float* __restrict__ scal_hh,
        int t) {
    const int l = blockIdx.z;
    const int nt0 = blockIdx.x * 2;
    const int tid = threadIdx.x;
    const int w = tid >> 6, lane = tid & 63;
    // prefetch gate operands early for both items (threads 0..127)
    float pv[4], swv[4];
    const int item_g = tid >> 6;
    const int b_g = tid & 15, jq_g = (tid >> 4) & 3;
    const int nt_g = nt0 + item_g;
    const int jc_g = nt_g * 4 + jq_g;
    if (tid < 128) {
        #pragma unroll
        for (int q = 0; q < 4; ++q) {
            const int row = nt_g * 16 + jq_g * 4 + q;
            pv[q]  = b2f(preT[((size_t)l * NPR_ + row) * 512 + t * 16 + b_g]);
            swv[q] = sW[(size_t)l * NPR_ + row] * (1.f / 127.f);
        }
    }
    const signed char* wbase = Wq8 + (((size_t)l * NTIL_ + nt0) * 40 + w * 10) * 1024 + lane * 16;
    const signed char* hbase = h_in + (size_t)l * 81920 + (w * 10) * 1024 + lane * 16;
    i32x4 s0h = {0, 0, 0, 0}, s0l = {0, 0, 0, 0};
    i32x4 s1h = {0, 0, 0, 0}, s1l = {0, 0, 0, 0};
    #pragma unroll 5
    for (int ks = 0; ks < 10; ++ks) {
        i32x4 ah = *(const i32x4*)(hbase + ks * 1024);
        i32x4 al = *(const i32x4*)(hbase + 40960 + ks * 1024);
        i32x4 b0 = *(const i32x4*)(wbase + ks * 1024);
        i32x4 b1 = *(const i32x4*)(wbase + 40960 + ks * 1024);
        s0h = __builtin_amdgcn_mfma_i32_16x16x64_i8(ah, b0, s0h, 0, 0, 0);
        s0l = __builtin_amdgcn_mfma_i32_16x16x64_i8(al, b0, s0l, 0, 0, 0);
        s1h = __builtin_amdgcn_mfma_i32_16x16x64_i8(ah, b1, s1h, 0, 0, 0);
        s1l = __builtin_amdgcn_mfma_i32_16x16x64_i8(al, b1, s1l, 0, 0, 0);
    }
    __shared__ float gl[2][4][16][17];
    const int col = lane & 15;
    const int m0 = (lane >> 4) * 4;
    #pragma unroll
    for (int v = 0; v < 4; ++v) {
        gl[0][w][col][m0 + v] = (float)s0h[v] + (float)s0l[v] * (1.f / 127.f);
        gl[1][w][col][m0 + v] = (float)s1h[v] + (float)s1l[v] * (1.f / 127.f);
    }
    __syncthreads();
    // gate pass: threads 0..127, one (item, unit, batch) each
    if (tid < 128 && jc_g < NC_) {
        float g[4];
        #pragma unroll
        for (int q = 0; q < 4; ++q) {
            float s = gl[item_g][0][jq_g * 4 + q][b_g] + gl[item_g][1][jq_g * 4 + q][b_g]
                    + gl[item_g][2][jq_g * 4 + q][b_g] + gl[item_g][3][jq_g * 4 + q][b_g];
            g[q] = s * swv[q] + pv[q];
        }
        float* cp = cst + ((size_t)l * NC_ + jc_g) * B_ + b_g;
        float ci = *cp;
        float cn = sigf(g[1]) * ci + sigf(g[0]) * tanhf(g[2]);
        float hn = sigf(g[3]) * tanhf(cn);
        *cp = cn;
        const int ks = jc_g >> 6, kgrp = (jc_g >> 4) & 3, e = jc_g & 15;
        const size_t off = (size_t)l * 81920 + (size_t)ks * 1024 + (kgrp * 16 + b_g) * 16 + e;
        float t1 = hn * 127.f;
        float fhi = rintf(t1);
        float flo = rintf((t1 - fhi) * 127.f);
        h_out[off]         = (signed char)(int)fhi;
        h_out[off + 40960] = (signed char)(int)flo;
        float sc = (l ? scal_hh : scal_ih)[jc_g];
        hbuf[(((size_t)l * T_ + t) * B_ + b_g) * NC_ + jc_g] = hn * sc;
    }
}

// Bt[k][h] = idct_hid[h][k] for k < 71
__global__ void k_bt(const float* __restrict__ Bh, float* __restrict__ Bt) {
    int idx = blockIdx.x * 256 + threadIdx.x;
    if (idx < NR_ * H_) {
        int k = idx / H_, h = idx - k * H_;
        Bt[idx] = Bh[(size_t)h * H_ + k];
    }
}

// yih[t,b,h] = sum_k Bt[k,h] * v[k]; coeffs pre-scaled in hbuf
__global__ __launch_bounds__(256) void k_yih(const float* __restrict__ x,
        const float* __restrict__ Ain, const float* __restrict__ Bt,
        const float* __restrict__ hbuf0, float* __restrict__ yih) {
    __shared__ float xl[I_];
    __shared__ float u[NR_];
    __shared__ float v[NR_];
    int tb = blockIdx.x;
    int tid = threadIdx.x;
    xl[tid] = x[(size_t)tb * I_ + tid];
    xl[tid + 256] = x[(size_t)tb * I_ + tid + 256];
    __syncthreads();
    if (tid < NR_) {
        float a = 0.f;
        for (int jj = 0; jj < I_; ++jj) a += Ain[(size_t)jj * I_ + tid] * xl[jj];
        u[tid] = a;
    }
    __syncthreads();
    if (tid < NR_) {
        int k = tid;
        int start = k * NR_ - (k * (k - 1)) / 2;
        int cnt = NR_ - k;
        const float* cf = hbuf0 + (size_t)tb * NC_;
        float a = 0.f;
        for (int m = 0; m < cnt; ++m) a += cf[start + m] * u[cnt - 1 - m];
        v[k] = a;
    }
    __syncthreads();
    for (int h = tid; h < H_; h += 256) {
        float a = 0.f;
        #pragma unroll
        for (int k = 0; k < NR_; ++k) a += Bt[(size_t)k * H_ + h] * v[k];
        yih[(size_t)tb * H_ + h] = a;
    }
}

// sequential phase-2: Bt in LDS pitch 520, b128-aligned; dbuf hl -> 3 barriers/step
#define BTP_ 520
__global__ __launch_bounds__(576) void k_seq(const float* __restrict__ yih,
        const float* __restrict__ Bt, const float* __restrict__ cf_all,
        const float* __restrict__ bias, float* __restrict__ out) {
    __shared__ __align__(16) float bt[NR_ * BTP_];   // 147.7 KB
    __shared__ __align__(16) float hl[2][H_];
    __shared__ float u[NR_ + 1];
    __shared__ __align__(16) float v[NR_ + 1];
    const int b = blockIdx.x, tid = threadIdx.x;
    for (int i = tid; i < NR_ * H_; i += 576)
        bt[(i >> 9) * BTP_ + (i & 511)] = Bt[i];
    for (int i = tid; i < H_; i += 576) hl[0][i] = 0.f;
    if (tid == 0) { u[NR_] = 0.f; v[NR_] = 0.f; }
    const float bv = (tid < H_) ? bias[tid] : 0.f;
    const int g = tid >> 3, lane = tid & 7;
    int start = 0, cnt = 0;
    if (g < NR_) { start = g * NR_ - (g * (g - 1)) / 2; cnt = NR_ - g; }
    int p = 0;
    __syncthreads();
    for (int t = 0; t < T_; ++t) {
        float cfv[9];
        if (g < NR_) {
            const float* cf = cf_all + ((size_t)t * B_ + b) * NC_ + start;
            #pragma unroll
            for (int mi = 0; mi < 9; ++mi) {
                int m = mi * 8 + lane;
                cfv[mi] = cf[m < cnt ? m : (cnt - 1)];
            }
        }
        if (g < NR_) {
            const float* bp = bt + g * BTP_ + lane * 4;
            const float* hp = hl[p] + lane * 4;
            float a = 0.f;
            #pragma unroll
            for (int m = 0; m < 16; ++m) {
                float4 bq = *(const float4*)(bp + m * 32);
                float4 hq = *(const float4*)(hp + m * 32);
                a += bq.x * hq.x + bq.y * hq.y + bq.z * hq.z + bq.w * hq.w;
            }
            a += __shfl_xor(a, 1); a += __shfl_xor(a, 2); a += __shfl_xor(a, 4);
            if (lane == 0) u[g] = a;
        }
        __syncthreads();
        if (g < NR_) {
            float a = 0.f;
            #pragma unroll
            for (int mi = 0; mi < 9; ++mi) {
                int m = mi * 8 + lane;
                a += (m < cnt) ? cfv[mi] * u[cnt - 1 - m] : 0.f;
            }
            a += __shfl_xor(a, 1); a += __shfl_xor(a, 2); a += __shfl_xor(a, 4);
            if (lane == 0) v[g] = a;
        }
        __syncthreads();
        if (tid < H_) {
            float4 vv[18];
            #pragma unroll
            for (int q = 0; q < 18; ++q) vv[q] = *(const float4*)(v + q * 4);
            float a0 = 0.f, a1 = 0.f;
            #pragma unroll
            for (int k = 0; k < NR_; ++k) {
                float vk = ((const float*)vv)[k];
                ((k & 1) ? a1 : a0) += bt[k * BTP_ + tid] * vk;
            }
            float hv = tanhf(yih[((size_t)t * B_ + b) * H_ + tid] + a0 + a1 + bv);
            out[((size_t)t * B_ + b) * H_ + tid] = hv;
            hl[p ^ 1][tid] = hv;
        }
        __syncthreads();
        p ^= 1;
    }
}

extern "C" void kernel_launch(void* const* d_in, const int* in_sizes, int n_in,
                              void* d_out, int out_size, void* d_ws, size_t ws_size,
                              hipStream_t stream) {
    const float* x        = (const float*)d_in[0];
    const float* wih_ih   = (const float*)d_in[1];
    const float* wih_hh   = (const float*)d_in[2];
    const float* wih_b    = (const float*)d_in[3];
    const float* whh_ih   = (const float*)d_in[4];
    const float* whh_hh   = (const float*)d_in[5];
    const float* whh_b    = (const float*)d_in[6];
    const float* scal_ih  = (const float*)d_in[7];
    const float* scal_hh  = (const float*)d_in[8];
    const float* bias     = (const float*)d_in[9];
    const float* idct_in  = (const float*)d_in[10];
    const float* idct_hid = (const float*)d_in[11];
    float* out = (float*)d_out;

    const size_t WP8_B  = (size_t)2 * NPR_ * NCP_;        //  52,428,800 (int8, K64-interleaved)
    const size_t SW_B   = (size_t)2 * NPR_ * 4;           //      81,920
    const size_t PRET_B = (size_t)2 * NPR_ * 512 * 2;     //  20,971,520
    const size_t HBUF_B = (size_t)2 * T_ * B_ * NC_ * 4;  //  10,469,376
    const size_t HBF_B  = (size_t)2 * 2 * 2 * 40960;      //     327,680 (pp x layer x hi/lo)
    const size_t CST_B  = (size_t)2 * NC_ * B_ * 4;       //     327,168
    const size_t YIH_B  = (size_t)T_ * B_ * H_ * 4;
    const size_t BT_B   = (size_t)NR_ * H_ * 4;
    const size_t need = WP8_B + SW_B + PRET_B + HBUF_B + HBF_B + CST_B + YIH_B + BT_B + 4096;

    char* ws = (char*)d_ws;
    size_t off = 0;
    auto alloc = [&](size_t bytes) -> void* {
        void* p = (void*)(ws + off);
        off += (bytes + 255) & ~(size_t)255;
        return p;
    };

    if (ws_size < need) return;   // harness workspace has always been >160MB

    signed char* Wp8 = (signed char*)alloc(WP8_B);
    float*  sW   = (float*)alloc(SW_B);
    ushort* preT = (ushort*)alloc(PRET_B);
    float*  hbuf = (float*)alloc(HBUF_B);
    signed char* hbf = (signed char*)alloc(HBF_B);
    float*  cst  = (float*)alloc(CST_B);
    float*  yih  = (float*)alloc(YIH_B);
    float*  Bt   = (float*)alloc(BT_B);
    // aliases inside Wp8 region (dead before k_cvt_whh_i8 runs)
    ushort* Wih_p = (ushort*)Wp8;                      // 21.0 MB
    ushort* Xbf   = (ushort*)((char*)Wp8 + 21000192);  // +0.5 MB, < 52.4 MB

    {   // zero hbf (pp x hi/lo incl. K-pad) + cst (contiguous allocs)
        int n = (int)((HBF_B + CST_B) / 4);
        hipLaunchKernelGGL(k_zero, dim3((n + 255) / 256), dim3(256), 0, stream,
                           (float*)hbf, n);
    }
    hipLaunchKernelGGL(k_cvt_x, dim3(256), dim3(256), 0, stream, x, Xbf);
    hipLaunchKernelGGL(k_cvt_w512p, dim3(NPR_ * 128 / 256, 1, 2), dim3(256), 0, stream,
                       wih_ih, whh_ih, Wih_p);
    hipLaunchKernelGGL(k_gih_mfma, dim3(160, 1, 2), dim3(256), 0, stream,
                       Xbf, Wih_p, wih_b, whh_b, preT);
    hipLaunchKernelGGL(k_cvt_whh_i8, dim3(NPR_ / 4, 1, 2), dim3(256), 0, stream,
                       wih_hh, whh_hh, Wp8, sW);

    const size_t HS = (size_t)2 * 81920;   // bytes per ping-pong buffer (2 layers)
    for (int t = 0; t < T_; ++t) {
        const signed char* hin  = hbf + (size_t)(t & 1) * HS;
        signed char*       hout = hbf + (size_t)((t & 1) ^ 1) * HS;
        hipLaunchKernelGGL(k_step, dim3(NTIL_ / 2, 1, 2), dim3(256), 0, stream,
                           Wp8, sW, preT, hin, hout, cst, hbuf, scal_ih, scal_hh, t);
    }

    hipLaunchKernelGGL(k_bt, dim3((NR_ * H_ + 255) / 256), dim3(256), 0, stream,
                       idct_hid, Bt);
    hipLaunchKernelGGL(k_yih, dim3(T_ * B_), dim3(256), 0, stream,
                       x, idct_in, Bt, hbuf, yih);
    hipLaunchKernelGGL(k_seq, dim3(B_), dim3(576), 0, stream,
                       yih, Bt, hbuf + (size_t)T_ * B_ * NC_, bias, out);
}